// Round 1
// baseline (2114.072 us; speedup 1.0000x reference)
//
#include <hip/hip_runtime.h>
#include <cstdint>
#include <cstddef>

#define N_NODES 20000
#define HD 256

typedef float f32x4 __attribute__((ext_vector_type(4)));
typedef unsigned short u16x8 __attribute__((ext_vector_type(8)));
typedef __bf16 bf16x8 __attribute__((ext_vector_type(8)));

static __device__ __forceinline__ bf16x8 asbf(u16x8 u) {
    return __builtin_bit_cast(bf16x8, u);
}
static __device__ __forceinline__ unsigned short f2b(float f) {
    unsigned u = __builtin_bit_cast(unsigned, f);
    u += 0x7FFFu + ((u >> 16) & 1u);   // round-to-nearest-even
    return (unsigned short)(u >> 16);
}
static __device__ __forceinline__ u16x8 pack8(float4 a, float4 b) {
    u16x8 r;
    r[0] = f2b(a.x); r[1] = f2b(a.y); r[2] = f2b(a.z); r[3] = f2b(a.w);
    r[4] = f2b(b.x); r[5] = f2b(b.y); r[6] = f2b(b.z); r[7] = f2b(b.w);
    return r;
}
static __device__ __forceinline__ float sigm(float z) {
    return 1.f / (1.f + __expf(-z));
}
static __device__ __forceinline__ float tanh_f(float z) {
    // safe everywhere: exp->inf gives 1-0=1, exp->0 gives -1
    return 1.f - 2.f / (__expf(2.f * z) + 1.f);
}

// ---------------------------------------------------------------------------
// K0a: weights -> bf16. ufb = U_f (g-major), wfb = W_f (g-major),
// b2t[g3][kk] = kk<256 ? U_iou[g3][kk] : W_iou[g3][kk-256]   (768 x 512)
// ---------------------------------------------------------------------------
__global__ void prep_weights(const float* __restrict__ Uf, const float* __restrict__ Wf,
                             const float* __restrict__ Uiou, const float* __restrict__ Wiou,
                             unsigned short* __restrict__ ufb, unsigned short* __restrict__ wfb,
                             unsigned short* __restrict__ b2t) {
    int i = blockIdx.x * blockDim.x + threadIdx.x;
    const int total = 65536 + 65536 + 768 * 512;
    for (; i < total; i += gridDim.x * blockDim.x) {
        if (i < 65536) {
            ufb[i] = f2b(Uf[i]);
        } else if (i < 131072) {
            wfb[i - 65536] = f2b(Wf[i - 65536]);
        } else {
            int j = i - 131072;
            int g = j >> 9, kk = j & 511;
            float v = (kk < 256) ? Uiou[g * 256 + kk] : Wiou[g * 256 + kk - 256];
            b2t[j] = f2b(v);
        }
    }
}

// ---------------------------------------------------------------------------
// K0b: XWF = x @ W_f^T + b_f   (N x 256, fp32 out)
// one wave per 16-row group; MFMA 16x16x32 bf16; B-frags straight from L2
// ---------------------------------------------------------------------------
__global__ void xwf_gemm(const float* __restrict__ x, const unsigned short* __restrict__ wfb,
                         const float* __restrict__ bf, float* __restrict__ xwf) {
    int lane = threadIdx.x & 63;
    int wid = (blockIdx.x * blockDim.x + threadIdx.x) >> 6;
    int nw = (gridDim.x * blockDim.x) >> 6;
    int r15 = lane & 15, q = lane >> 4;
    const int NG = N_NODES / 16;
    for (int grp = wid; grp < NG; grp += nw) {
        int n = grp * 16 + r15;
        u16x8 afr[8];
        const float4* xp = reinterpret_cast<const float4*>(x + (size_t)n * 256 + q * 8);
#pragma unroll
        for (int kt = 0; kt < 8; kt++) {
            float4 a0 = xp[kt * 8];
            float4 a1 = xp[kt * 8 + 1];
            afr[kt] = pack8(a0, a1);
        }
        const unsigned short* bbase = wfb + r15 * 256 + q * 8;
#pragma unroll
        for (int ct = 0; ct < 16; ct++) {
            float bv = bf[ct * 16 + r15];
            f32x4 acc = {bv, bv, bv, bv};
#pragma unroll
            for (int kt = 0; kt < 8; kt++) {
                u16x8 b = *reinterpret_cast<const u16x8*>(bbase + ct * 4096 + kt * 32);
                acc = __builtin_amdgcn_mfma_f32_16x16x32_bf16(asbf(afr[kt]), asbf(b), acc, 0, 0, 0);
            }
#pragma unroll
            for (int j = 0; j < 4; j++) {
                int row = grp * 16 + q * 4 + j;
                xwf[(size_t)row * 256 + ct * 16 + r15] = acc[j];
            }
        }
    }
}

// ---------------------------------------------------------------------------
// K1: main streamer. One wave per node n.
//   h_m = h_mail + time_mail              -> bf16 A-frags (16 mails x 256)
//   h_tild = sum_k mask*h_m               -> shfl_xor butterfly, bf16 to ws
//   f = sigmoid(h_m @ U_f^T + XWF[n])     -> 16 col-tiles x 8 MFMA
//   c_red = sum_k mask*f*c_mail           -> fp32 to ws
// ---------------------------------------------------------------------------
__global__ void main_cell(const float* __restrict__ h_mail, const float* __restrict__ c_mail,
                          const float* __restrict__ time_mail, const float* __restrict__ mask,
                          const float* __restrict__ xwf, const unsigned short* __restrict__ ufb,
                          unsigned short* __restrict__ htb, float* __restrict__ c_redw) {
    int lane = threadIdx.x & 63;
    int wid = (blockIdx.x * blockDim.x + threadIdx.x) >> 6;
    int nw = (gridDim.x * blockDim.x) >> 6;
    int r15 = lane & 15, q = lane >> 4;
    for (int n = wid; n < N_NODES; n += nw) {
        size_t rowbase = ((size_t)n * 16 + r15) * 256 + q * 8;
        const float4* hp = reinterpret_cast<const float4*>(h_mail + rowbase);
        const float4* tp = reinterpret_cast<const float4*>(time_mail + rowbase);
        float4 m4 = reinterpret_cast<const float4*>(mask + (size_t)n * 16)[q];
        float mrow = mask[(size_t)n * 16 + r15];

        u16x8 afr[8];
#pragma unroll
        for (int kt = 0; kt < 8; kt++) {
            float4 h0 = hp[kt * 8], h1 = hp[kt * 8 + 1];
            float4 t0 = tp[kt * 8], t1 = tp[kt * 8 + 1];
            float4 s0 = {h0.x + t0.x, h0.y + t0.y, h0.z + t0.z, h0.w + t0.w};
            float4 s1 = {h1.x + t1.x, h1.y + t1.y, h1.z + t1.z, h1.w + t1.w};
            afr[kt] = pack8(s0, s1);
            // h_tild partial: mask[row]*h_m, reduce over the 16 rows (lane bits 0..3)
            float v0 = mrow * s0.x, v1 = mrow * s0.y, v2 = mrow * s0.z, v3 = mrow * s0.w;
            float v4 = mrow * s1.x, v5 = mrow * s1.y, v6 = mrow * s1.z, v7 = mrow * s1.w;
#pragma unroll
            for (int m = 1; m < 16; m <<= 1) {
                v0 += __shfl_xor(v0, m, 64); v1 += __shfl_xor(v1, m, 64);
                v2 += __shfl_xor(v2, m, 64); v3 += __shfl_xor(v3, m, 64);
                v4 += __shfl_xor(v4, m, 64); v5 += __shfl_xor(v5, m, 64);
                v6 += __shfl_xor(v6, m, 64); v7 += __shfl_xor(v7, m, 64);
            }
            if (r15 == 0) {
                float4 w0 = {v0, v1, v2, v3};
                float4 w1 = {v4, v5, v6, v7};
                *reinterpret_cast<u16x8*>(htb + (size_t)n * 256 + kt * 32 + q * 8) = pack8(w0, w1);
            }
        }

        const unsigned short* bbase = ufb + r15 * 256 + q * 8;
        const float* cmbase = c_mail + ((size_t)n * 16 + q * 4) * 256 + r15;
        float mj0 = m4.x, mj1 = m4.y, mj2 = m4.z, mj3 = m4.w;
#pragma unroll
        for (int ct = 0; ct < 16; ct++) {
            float xv = xwf[(size_t)n * 256 + ct * 16 + r15];
            f32x4 acc = {xv, xv, xv, xv};
#pragma unroll
            for (int kt = 0; kt < 8; kt++) {
                u16x8 b = *reinterpret_cast<const u16x8*>(bbase + ct * 4096 + kt * 32);
                acc = __builtin_amdgcn_mfma_f32_16x16x32_bf16(asbf(afr[kt]), asbf(b), acc, 0, 0, 0);
            }
            float s = 0.f;
            s += mj0 * sigm(acc[0]) * cmbase[ct * 16];
            s += mj1 * sigm(acc[1]) * cmbase[256 + ct * 16];
            s += mj2 * sigm(acc[2]) * cmbase[512 + ct * 16];
            s += mj3 * sigm(acc[3]) * cmbase[768 + ct * 16];
            s += __shfl_xor(s, 16, 64);
            s += __shfl_xor(s, 32, 64);
            if (lane < 16) c_redw[(size_t)n * 256 + ct * 16 + lane] = s;
        }
    }
}

// ---------------------------------------------------------------------------
// K2: iou = [h_tild | x] @ [U_iou | W_iou]^T + b_iou ; gates -> h, c
// one wave per 16-row group; i/o/u col-tiles computed together so gating is
// in-register. c_red added; h -> out[0:N*256), c -> out[N*256:2*N*256)
// ---------------------------------------------------------------------------
__global__ void iou_final(const unsigned short* __restrict__ htb, const float* __restrict__ x,
                          const float* __restrict__ c_redw, const unsigned short* __restrict__ b2t,
                          const float* __restrict__ biou, float* __restrict__ out) {
    int lane = threadIdx.x & 63;
    int wid = (blockIdx.x * blockDim.x + threadIdx.x) >> 6;
    int nw = (gridDim.x * blockDim.x) >> 6;
    int r15 = lane & 15, q = lane >> 4;
    const int NG = N_NODES / 16;
    const size_t NH = (size_t)N_NODES * 256;
    for (int grp = wid; grp < NG; grp += nw) {
        int n = grp * 16 + r15;
        u16x8 afr[16];
#pragma unroll
        for (int kt = 0; kt < 8; kt++)
            afr[kt] = *reinterpret_cast<const u16x8*>(htb + (size_t)n * 256 + kt * 32 + q * 8);
        const float4* xp = reinterpret_cast<const float4*>(x + (size_t)n * 256 + q * 8);
#pragma unroll
        for (int kt = 0; kt < 8; kt++) {
            float4 a0 = xp[kt * 8], a1 = xp[kt * 8 + 1];
            afr[8 + kt] = pack8(a0, a1);
        }
        const unsigned short* bb = b2t + (size_t)r15 * 512 + q * 8;
#pragma unroll
        for (int g = 0; g < 16; g++) {
            float bi = biou[g * 16 + r15];
            float bo = biou[256 + g * 16 + r15];
            float bu = biou[512 + g * 16 + r15];
            f32x4 ai = {bi, bi, bi, bi};
            f32x4 ao = {bo, bo, bo, bo};
            f32x4 au = {bu, bu, bu, bu};
#pragma unroll
            for (int kt = 0; kt < 16; kt++) {
                u16x8 Bi = *reinterpret_cast<const u16x8*>(bb + (size_t)(g * 16) * 512 + kt * 32);
                u16x8 Bo = *reinterpret_cast<const u16x8*>(bb + (size_t)(256 + g * 16) * 512 + kt * 32);
                u16x8 Bu = *reinterpret_cast<const u16x8*>(bb + (size_t)(512 + g * 16) * 512 + kt * 32);
                ai = __builtin_amdgcn_mfma_f32_16x16x32_bf16(asbf(afr[kt]), asbf(Bi), ai, 0, 0, 0);
                ao = __builtin_amdgcn_mfma_f32_16x16x32_bf16(asbf(afr[kt]), asbf(Bo), ao, 0, 0, 0);
                au = __builtin_amdgcn_mfma_f32_16x16x32_bf16(asbf(afr[kt]), asbf(Bu), au, 0, 0, 0);
            }
#pragma unroll
            for (int j = 0; j < 4; j++) {
                int row = grp * 16 + q * 4 + j;
                size_t o = (size_t)row * 256 + g * 16 + r15;
                float cr = c_redw[o];
                float c = sigm(ai[j]) * tanh_f(au[j]) + cr;
                float h = sigm(ao[j]) * tanh_f(c);
                out[o] = h;
                out[NH + o] = c;
            }
        }
    }
}

extern "C" void kernel_launch(void* const* d_in, const int* in_sizes, int n_in,
                              void* d_out, int out_size, void* d_ws, size_t ws_size,
                              hipStream_t stream) {
    const float* x         = (const float*)d_in[0];
    const float* h_mail    = (const float*)d_in[1];
    const float* c_mail    = (const float*)d_in[2];
    const float* time_mail = (const float*)d_in[3];
    const float* mask      = (const float*)d_in[4];
    const float* W_iou     = (const float*)d_in[5];
    const float* U_iou     = (const float*)d_in[6];
    const float* b_iou     = (const float*)d_in[7];
    const float* U_f       = (const float*)d_in[8];
    const float* W_f       = (const float*)d_in[9];
    const float* b_f       = (const float*)d_in[10];
    float* out = (float*)d_out;

    char* w = (char*)d_ws;
    unsigned short* ufb    = (unsigned short*)(w);              // 128 KB
    unsigned short* wfb    = (unsigned short*)(w + 131072);     // 128 KB
    unsigned short* b2t    = (unsigned short*)(w + 262144);     // 768 KB
    unsigned short* htb    = (unsigned short*)(w + 1048576);    // 10.24 MB (bf16 h_tild)
    float*          xwf    = (float*)(w + 11288576);            // 20.48 MB
    float*          c_redw = (float*)(w + 31768576);            // 20.48 MB
    // total ws usage: 52,248,576 bytes

    prep_weights<<<512, 256, 0, stream>>>(U_f, W_f, U_iou, W_iou, ufb, wfb, b2t);
    xwf_gemm<<<320, 256, 0, stream>>>(x, wfb, b_f, xwf);
    main_cell<<<1024, 256, 0, stream>>>(h_mail, c_mail, time_mail, mask, xwf, ufb, htb, c_redw);
    iou_final<<<320, 256, 0, stream>>>(htb, x, c_redw, b2t, b_iou, out);
}

// Round 2
// 649.216 us; speedup vs baseline: 3.2563x; 3.2563x over previous
//
#include <hip/hip_runtime.h>
#include <cstdint>
#include <cstddef>

#define N_NODES 20000

typedef float f32x4 __attribute__((ext_vector_type(4)));
typedef unsigned short u16x8 __attribute__((ext_vector_type(8)));
typedef __bf16 bf16x8 __attribute__((ext_vector_type(8)));

static __device__ __forceinline__ bf16x8 asbf(u16x8 u) {
    return __builtin_bit_cast(bf16x8, u);
}
static __device__ __forceinline__ unsigned short f2b(float f) {
    unsigned u = __builtin_bit_cast(unsigned, f);
    u += 0x7FFFu + ((u >> 16) & 1u);   // round-to-nearest-even
    return (unsigned short)(u >> 16);
}
static __device__ __forceinline__ float b2f(unsigned short u) {
    return __builtin_bit_cast(float, (unsigned)u << 16);
}
static __device__ __forceinline__ u16x8 pack8(f32x4 a, f32x4 b) {
    u16x8 r;
    r[0] = f2b(a[0]); r[1] = f2b(a[1]); r[2] = f2b(a[2]); r[3] = f2b(a[3]);
    r[4] = f2b(b[0]); r[5] = f2b(b[1]); r[6] = f2b(b[2]); r[7] = f2b(b[3]);
    return r;
}
static __device__ __forceinline__ float sigm(float z) {
    return 1.f / (1.f + __expf(-z));
}
static __device__ __forceinline__ float tanh_f(float z) {
    return 1.f - 2.f / (__expf(2.f * z) + 1.f);
}

// ---------------------------------------------------------------------------
// K0a: weights -> bf16 in MFMA-FRAGMENT order.
//  ufrag/wfrag: idx = ((ct*8+kt)*64 + lane)*8 + e
//      g = ct*16 + (lane&15), k = kt*32 + (lane>>4)*8 + e   (256x256)
//  b2frag:      idx = ((ct3*16+kt)*64 + lane)*8 + e, ct3 in [0,48)
//      g3 = ct3*16 + (lane&15), kk = kt*32 + (lane>>4)*8 + e
//      val = kk<256 ? U_iou[g3][kk] : W_iou[g3][kk-256]
// ---------------------------------------------------------------------------
__global__ void prep_weights(const float* __restrict__ Uf, const float* __restrict__ Wf,
                             const float* __restrict__ Uiou, const float* __restrict__ Wiou,
                             unsigned short* __restrict__ ufrag, unsigned short* __restrict__ wfrag,
                             unsigned short* __restrict__ b2frag) {
    const int NU = 256 * 256;
    const int NB = 768 * 512;
    int i = blockIdx.x * blockDim.x + threadIdx.x;
    const int total = NU + NU + NB;
    for (; i < total; i += gridDim.x * blockDim.x) {
        if (i < 2 * NU) {
            int j = (i < NU) ? i : i - NU;
            int e = j & 7, lane = (j >> 3) & 63, kt = (j >> 9) & 7, ct = j >> 12;
            int g = ct * 16 + (lane & 15);
            int k = kt * 32 + (lane >> 4) * 8 + e;
            if (i < NU) ufrag[j] = f2b(Uf[g * 256 + k]);
            else        wfrag[j] = f2b(Wf[g * 256 + k]);
        } else {
            int j = i - 2 * NU;
            int e = j & 7, lane = (j >> 3) & 63, kt = (j >> 9) & 15, ct3 = j >> 13;
            int g3 = ct3 * 16 + (lane & 15);
            int kk = kt * 32 + (lane >> 4) * 8 + e;
            float v = (kk < 256) ? Uiou[g3 * 256 + kk] : Wiou[g3 * 256 + kk - 256];
            b2frag[j] = f2b(v);
        }
    }
}

// ---------------------------------------------------------------------------
// K0b: XWF = x @ W_f^T + b_f   (N x 256 fp32). B-frags coalesced from wfrag.
// ---------------------------------------------------------------------------
__global__ __launch_bounds__(256, 2) void xwf_gemm(const float* __restrict__ x,
                         const unsigned short* __restrict__ wfrag,
                         const float* __restrict__ bf, float* __restrict__ xwf) {
    int lane = threadIdx.x & 63;
    int wid = (blockIdx.x * blockDim.x + threadIdx.x) >> 6;
    int nw = (gridDim.x * blockDim.x) >> 6;
    int r15 = lane & 15, q = lane >> 4;
    const int NG = N_NODES / 16;
    for (int grp = wid; grp < NG; grp += nw) {
        int n0 = grp * 16;
        const f32x4* xp = reinterpret_cast<const f32x4*>(x + ((size_t)(n0 + r15)) * 256 + q * 8);
        u16x8 afr[8];
#pragma unroll
        for (int kt = 0; kt < 8; kt++) {
            f32x4 a0 = __builtin_nontemporal_load(xp + kt * 8);
            f32x4 a1 = __builtin_nontemporal_load(xp + kt * 8 + 1);
            afr[kt] = pack8(a0, a1);
        }
#pragma unroll
        for (int ct = 0; ct < 16; ct++) {
            float bv = bf[ct * 16 + r15];
            f32x4 acc = {bv, bv, bv, bv};
#pragma unroll
            for (int kt = 0; kt < 8; kt++) {
                u16x8 b = *reinterpret_cast<const u16x8*>(wfrag + ((size_t)(ct * 8 + kt) * 64 + lane) * 8);
                acc = __builtin_amdgcn_mfma_f32_16x16x32_bf16(asbf(afr[kt]), asbf(b), acc, 0, 0, 0);
            }
#pragma unroll
            for (int j = 0; j < 4; j++) {
                __builtin_nontemporal_store(acc[j], &xwf[(size_t)(n0 + q * 4 + j) * 256 + ct * 16 + r15]);
            }
        }
    }
}

// ---------------------------------------------------------------------------
// K1: main streamer. One wave per node.
//   afr = bf16(h_mail + time_mail)  (16x256 A-frags, coalesced nt loads)
//   h_tild via shfl butterfly from afr -> htb (bf16)
//   f = sigmoid(h_m @ U_f^T + XWF[n]); c_red = sum_k mask*f*c_mail -> c_redw
// U_f frags from ufrag: coalesced, L2-resident (streams are nt).
// ---------------------------------------------------------------------------
__global__ __launch_bounds__(256, 4) void main_cell(
        const float* __restrict__ h_mail, const float* __restrict__ c_mail,
        const float* __restrict__ time_mail, const float* __restrict__ mask,
        const float* __restrict__ xwf, const unsigned short* __restrict__ ufrag,
        unsigned short* __restrict__ htb, float* __restrict__ c_redw) {
    int lane = threadIdx.x & 63;
    int wid = (blockIdx.x * blockDim.x + threadIdx.x) >> 6;
    int nw = (gridDim.x * blockDim.x) >> 6;
    int r15 = lane & 15, q = lane >> 4;
    for (int n = wid; n < N_NODES; n += nw) {
        size_t rowbase = ((size_t)n * 16 + r15) * 256 + q * 8;
        const f32x4* hp = reinterpret_cast<const f32x4*>(h_mail + rowbase);
        const f32x4* tp = reinterpret_cast<const f32x4*>(time_mail + rowbase);
        f32x4 m4 = *reinterpret_cast<const f32x4*>(mask + (size_t)n * 16 + q * 4);
        float mrow = mask[(size_t)n * 16 + r15];

        u16x8 afr[8];
#pragma unroll
        for (int kt = 0; kt < 8; kt++) {
            f32x4 h0 = __builtin_nontemporal_load(hp + kt * 8);
            f32x4 h1 = __builtin_nontemporal_load(hp + kt * 8 + 1);
            f32x4 t0 = __builtin_nontemporal_load(tp + kt * 8);
            f32x4 t1 = __builtin_nontemporal_load(tp + kt * 8 + 1);
            afr[kt] = pack8(h0 + t0, h1 + t1);
        }

        // h_tild: butterfly over the 16 mail rows (lane bits 0..3)
#pragma unroll
        for (int kt = 0; kt < 8; kt++) {
            float v[8];
#pragma unroll
            for (int e = 0; e < 8; e++) v[e] = mrow * b2f(afr[kt][e]);
#pragma unroll
            for (int m = 1; m < 16; m <<= 1) {
#pragma unroll
                for (int e = 0; e < 8; e++) v[e] += __shfl_xor(v[e], m, 64);
            }
            if (r15 == 0) {
                f32x4 w0 = {v[0], v[1], v[2], v[3]};
                f32x4 w1 = {v[4], v[5], v[6], v[7]};
                __builtin_nontemporal_store(pack8(w0, w1),
                    reinterpret_cast<u16x8*>(htb + (size_t)n * 256 + kt * 32 + q * 8));
            }
        }

        // f-GEMM + c_red, depth-1 prefetch of c_mail/xwf scalars
        const float* cmb = c_mail + ((size_t)n * 16 + q * 4) * 256 + r15;
        const float* xb = xwf + (size_t)n * 256 + r15;
        float mj0 = m4[0], mj1 = m4[1], mj2 = m4[2], mj3 = m4[3];
        float cm0 = __builtin_nontemporal_load(cmb);
        float cm1 = __builtin_nontemporal_load(cmb + 256);
        float cm2 = __builtin_nontemporal_load(cmb + 512);
        float cm3 = __builtin_nontemporal_load(cmb + 768);
        float xv  = __builtin_nontemporal_load(xb);
        for (int ct = 0; ct < 16; ct++) {
            float nc0 = cm0, nc1 = cm1, nc2 = cm2, nc3 = cm3, nx = xv;
            if (ct < 15) {
                nc0 = __builtin_nontemporal_load(cmb + (ct + 1) * 16);
                nc1 = __builtin_nontemporal_load(cmb + (ct + 1) * 16 + 256);
                nc2 = __builtin_nontemporal_load(cmb + (ct + 1) * 16 + 512);
                nc3 = __builtin_nontemporal_load(cmb + (ct + 1) * 16 + 768);
                nx  = __builtin_nontemporal_load(xb + (ct + 1) * 16);
            }
            f32x4 acc = {xv, xv, xv, xv};
#pragma unroll
            for (int kt = 0; kt < 8; kt++) {
                u16x8 b = *reinterpret_cast<const u16x8*>(ufrag + ((size_t)(ct * 8 + kt) * 64 + lane) * 8);
                acc = __builtin_amdgcn_mfma_f32_16x16x32_bf16(asbf(afr[kt]), asbf(b), acc, 0, 0, 0);
            }
            float s = mj0 * sigm(acc[0]) * cm0 + mj1 * sigm(acc[1]) * cm1
                    + mj2 * sigm(acc[2]) * cm2 + mj3 * sigm(acc[3]) * cm3;
            s += __shfl_xor(s, 16, 64);
            s += __shfl_xor(s, 32, 64);
            if (lane < 16)
                __builtin_nontemporal_store(s, &c_redw[(size_t)n * 256 + ct * 16 + lane]);
            cm0 = nc0; cm1 = nc1; cm2 = nc2; cm3 = nc3; xv = nx;
        }
    }
}

// ---------------------------------------------------------------------------
// K2: iou = [h_tild | x] @ [U_iou | W_iou]^T + b_iou ; gates -> h, c
// B-frags coalesced from b2frag (L2-resident); i/o/u of the same output
// columns computed together so gating stays in-register.
// ---------------------------------------------------------------------------
__global__ __launch_bounds__(256, 2) void iou_final(
        const unsigned short* __restrict__ htb, const float* __restrict__ x,
        const float* __restrict__ c_redw, const unsigned short* __restrict__ b2frag,
        const float* __restrict__ biou, float* __restrict__ out) {
    int lane = threadIdx.x & 63;
    int wid = (blockIdx.x * blockDim.x + threadIdx.x) >> 6;
    int nw = (gridDim.x * blockDim.x) >> 6;
    int r15 = lane & 15, q = lane >> 4;
    const int NG = N_NODES / 16;
    const size_t NH = (size_t)N_NODES * 256;
    for (int grp = wid; grp < NG; grp += nw) {
        int n0 = grp * 16;
        u16x8 afr[16];
#pragma unroll
        for (int kt = 0; kt < 8; kt++)
            afr[kt] = __builtin_nontemporal_load(
                reinterpret_cast<const u16x8*>(htb + (size_t)(n0 + r15) * 256 + kt * 32 + q * 8));
        const f32x4* xp = reinterpret_cast<const f32x4*>(x + (size_t)(n0 + r15) * 256 + q * 8);
#pragma unroll
        for (int kt = 0; kt < 8; kt++) {
            f32x4 a0 = __builtin_nontemporal_load(xp + kt * 8);
            f32x4 a1 = __builtin_nontemporal_load(xp + kt * 8 + 1);
            afr[8 + kt] = pack8(a0, a1);
        }
        for (int ct = 0; ct < 16; ct++) {
            // issue c_red loads early (independent of MFMAs)
            float cr[4];
#pragma unroll
            for (int j = 0; j < 4; j++)
                cr[j] = __builtin_nontemporal_load(
                    &c_redw[(size_t)(n0 + q * 4 + j) * 256 + ct * 16 + r15]);
            float bi = biou[ct * 16 + r15];
            float bo = biou[256 + ct * 16 + r15];
            float bu = biou[512 + ct * 16 + r15];
            f32x4 ai = {bi, bi, bi, bi};
            f32x4 ao = {bo, bo, bo, bo};
            f32x4 au = {bu, bu, bu, bu};
#pragma unroll
            for (int kt = 0; kt < 16; kt++) {
                u16x8 Bi = *reinterpret_cast<const u16x8*>(b2frag + ((size_t)((ct)      * 16 + kt) * 64 + lane) * 8);
                u16x8 Bo = *reinterpret_cast<const u16x8*>(b2frag + ((size_t)((16 + ct) * 16 + kt) * 64 + lane) * 8);
                u16x8 Bu = *reinterpret_cast<const u16x8*>(b2frag + ((size_t)((32 + ct) * 16 + kt) * 64 + lane) * 8);
                ai = __builtin_amdgcn_mfma_f32_16x16x32_bf16(asbf(afr[kt]), asbf(Bi), ai, 0, 0, 0);
                ao = __builtin_amdgcn_mfma_f32_16x16x32_bf16(asbf(afr[kt]), asbf(Bo), ao, 0, 0, 0);
                au = __builtin_amdgcn_mfma_f32_16x16x32_bf16(asbf(afr[kt]), asbf(Bu), au, 0, 0, 0);
            }
#pragma unroll
            for (int j = 0; j < 4; j++) {
                size_t o = (size_t)(n0 + q * 4 + j) * 256 + ct * 16 + r15;
                float c = sigm(ai[j]) * tanh_f(au[j]) + cr[j];
                float h = sigm(ao[j]) * tanh_f(c);
                __builtin_nontemporal_store(h, &out[o]);
                __builtin_nontemporal_store(c, &out[NH + o]);
            }
        }
    }
}

extern "C" void kernel_launch(void* const* d_in, const int* in_sizes, int n_in,
                              void* d_out, int out_size, void* d_ws, size_t ws_size,
                              hipStream_t stream) {
    const float* x         = (const float*)d_in[0];
    const float* h_mail    = (const float*)d_in[1];
    const float* c_mail    = (const float*)d_in[2];
    const float* time_mail = (const float*)d_in[3];
    const float* mask      = (const float*)d_in[4];
    const float* W_iou     = (const float*)d_in[5];
    const float* U_iou     = (const float*)d_in[6];
    const float* b_iou     = (const float*)d_in[7];
    const float* U_f       = (const float*)d_in[8];
    const float* W_f       = (const float*)d_in[9];
    const float* b_f       = (const float*)d_in[10];
    float* out = (float*)d_out;

    char* w = (char*)d_ws;
    unsigned short* ufrag  = (unsigned short*)(w);              // 128 KB
    unsigned short* wfrag  = (unsigned short*)(w + 131072);     // 128 KB
    unsigned short* b2frag = (unsigned short*)(w + 262144);     // 768 KB
    unsigned short* htb    = (unsigned short*)(w + 1048576);    // 10.24 MB
    float*          xwf    = (float*)(w + 11288576);            // 20.48 MB
    float*          c_redw = (float*)(w + 31768576);            // 20.48 MB

    prep_weights<<<512, 256, 0, stream>>>(U_f, W_f, U_iou, W_iou, ufrag, wfrag, b2frag);
    xwf_gemm<<<313, 256, 0, stream>>>(x, wfrag, b_f, xwf);
    main_cell<<<1024, 256, 0, stream>>>(h_mail, c_mail, time_mail, mask, xwf, ufrag, htb, c_redw);
    iou_final<<<313, 256, 0, stream>>>(htb, x, c_redw, b2frag, b_iou, out);
}

// Round 3
// 538.670 us; speedup vs baseline: 3.9246x; 1.2052x over previous
//
#include <hip/hip_runtime.h>
#include <cstdint>
#include <cstddef>

#define N_NODES 20000

typedef float f32x4 __attribute__((ext_vector_type(4)));
typedef unsigned short u16x8 __attribute__((ext_vector_type(8)));
typedef __bf16 bf16x8 __attribute__((ext_vector_type(8)));

static __device__ __forceinline__ bf16x8 asbf(u16x8 u) {
    return __builtin_bit_cast(bf16x8, u);
}
static __device__ __forceinline__ unsigned short f2b(float f) {
    unsigned u = __builtin_bit_cast(unsigned, f);
    u += 0x7FFFu + ((u >> 16) & 1u);   // round-to-nearest-even
    return (unsigned short)(u >> 16);
}
static __device__ __forceinline__ float b2f(unsigned short u) {
    return __builtin_bit_cast(float, (unsigned)u << 16);
}
static __device__ __forceinline__ u16x8 pack8(f32x4 a, f32x4 b) {
    u16x8 r;
    r[0] = f2b(a[0]); r[1] = f2b(a[1]); r[2] = f2b(a[2]); r[3] = f2b(a[3]);
    r[4] = f2b(b[0]); r[5] = f2b(b[1]); r[6] = f2b(b[2]); r[7] = f2b(b[3]);
    return r;
}
static __device__ __forceinline__ float sigm(float z) {
    return 1.f / (1.f + __expf(-z));
}
static __device__ __forceinline__ float tanh_f(float z) {
    return 1.f - 2.f / (__expf(2.f * z) + 1.f);
}

// ---------------------------------------------------------------------------
// K0a: weights -> bf16 in MFMA-FRAGMENT order.
//  ufrag/wfrag: idx = ((ct*8+kt)*64 + lane)*8 + e
//      g = ct*16 + (lane&15), k = kt*32 + (lane>>4)*8 + e   (256x256)
//  b2frag:      idx = ((ct3*16+kt)*64 + lane)*8 + e, ct3 in [0,48)
//      g3 = ct3*16 + (lane&15), kk = kt*32 + (lane>>4)*8 + e
//      val = kk<256 ? U_iou[g3][kk] : W_iou[g3][kk-256]
// ---------------------------------------------------------------------------
__global__ void prep_weights(const float* __restrict__ Uf, const float* __restrict__ Wf,
                             const float* __restrict__ Uiou, const float* __restrict__ Wiou,
                             unsigned short* __restrict__ ufrag, unsigned short* __restrict__ wfrag,
                             unsigned short* __restrict__ b2frag) {
    const int NU = 256 * 256;
    const int NB = 768 * 512;
    int i = blockIdx.x * blockDim.x + threadIdx.x;
    const int total = NU + NU + NB;
    for (; i < total; i += gridDim.x * blockDim.x) {
        if (i < 2 * NU) {
            int j = (i < NU) ? i : i - NU;
            int e = j & 7, lane = (j >> 3) & 63, kt = (j >> 9) & 7, ct = j >> 12;
            int g = ct * 16 + (lane & 15);
            int k = kt * 32 + (lane >> 4) * 8 + e;
            if (i < NU) ufrag[j] = f2b(Uf[g * 256 + k]);
            else        wfrag[j] = f2b(Wf[g * 256 + k]);
        } else {
            int j = i - 2 * NU;
            int e = j & 7, lane = (j >> 3) & 63, kt = (j >> 9) & 15, ct3 = j >> 13;
            int g3 = ct3 * 16 + (lane & 15);
            int kk = kt * 32 + (lane >> 4) * 8 + e;
            float v = (kk < 256) ? Uiou[g3 * 256 + kk] : Wiou[g3 * 256 + kk - 256];
            b2frag[j] = f2b(v);
        }
    }
}

// ---------------------------------------------------------------------------
// K0b: XWF = x @ W_f^T + b_f  (N x 256 fp32).
// Wave handles (group, ct-quad): 4 col-tiles each; 5000 waves total.
// ---------------------------------------------------------------------------
__global__ __launch_bounds__(256, 4) void xwf_gemm(const float* __restrict__ x,
                         const unsigned short* __restrict__ wfrag,
                         const float* __restrict__ bf, float* __restrict__ xwf) {
    int lane = threadIdx.x & 63;
    int wid = (blockIdx.x * blockDim.x + threadIdx.x) >> 6;
    int nw = (gridDim.x * blockDim.x) >> 6;
    int r15 = lane & 15, q = lane >> 4;
    const int NG = N_NODES / 16;
    for (int t = wid; t < NG * 4; t += nw) {
        int grp = t >> 2, cq = t & 3;
        int n0 = grp * 16;
        const f32x4* xp = reinterpret_cast<const f32x4*>(x + ((size_t)(n0 + r15)) * 256 + q * 8);
        u16x8 afr[8];
#pragma unroll
        for (int kt = 0; kt < 8; kt++) {
            f32x4 a0 = xp[kt * 8];
            f32x4 a1 = xp[kt * 8 + 1];
            afr[kt] = pack8(a0, a1);
        }
#pragma unroll
        for (int cc = 0; cc < 4; cc++) {
            int ct = cq * 4 + cc;
            float bv = bf[ct * 16 + r15];
            f32x4 acc = {bv, bv, bv, bv};
#pragma unroll
            for (int kt = 0; kt < 8; kt++) {
                u16x8 b = *reinterpret_cast<const u16x8*>(wfrag + ((size_t)(ct * 8 + kt) * 64 + lane) * 8);
                acc = __builtin_amdgcn_mfma_f32_16x16x32_bf16(asbf(afr[kt]), asbf(b), acc, 0, 0, 0);
            }
#pragma unroll
            for (int j = 0; j < 4; j++)
                xwf[(size_t)(n0 + q * 4 + j) * 256 + ct * 16 + r15] = acc[j];
        }
    }
}

// ---------------------------------------------------------------------------
// K1: main streamer. One wave per node (2 nodes/wave at grid 2500x256).
//   afr = bf16(h_mail + time_mail)  (nt loads: each line consumed once)
//   h_tild via shfl butterfly -> htb (plain stores, L2-merged)
//   f = sigmoid(h_m @ U_f^T + XWF[n]); c_red = sum_k mask*f*c_mail
//   c_mail/xwf plain loads: 128B lines reused across adjacent ct via L1.
// ---------------------------------------------------------------------------
__global__ __launch_bounds__(256, 4) void main_cell(
        const float* __restrict__ h_mail, const float* __restrict__ c_mail,
        const float* __restrict__ time_mail, const float* __restrict__ mask,
        const float* __restrict__ xwf, const unsigned short* __restrict__ ufrag,
        unsigned short* __restrict__ htb, float* __restrict__ c_redw) {
    int lane = threadIdx.x & 63;
    int wid = (blockIdx.x * blockDim.x + threadIdx.x) >> 6;
    int nw = (gridDim.x * blockDim.x) >> 6;
    int r15 = lane & 15, q = lane >> 4;
    for (int n = wid; n < N_NODES; n += nw) {
        size_t rowbase = ((size_t)n * 16 + r15) * 256 + q * 8;
        const f32x4* hp = reinterpret_cast<const f32x4*>(h_mail + rowbase);
        const f32x4* tp = reinterpret_cast<const f32x4*>(time_mail + rowbase);
        f32x4 m4 = *reinterpret_cast<const f32x4*>(mask + (size_t)n * 16 + q * 4);
        float mrow = mask[(size_t)n * 16 + r15];

        u16x8 afr[8];
#pragma unroll
        for (int kt = 0; kt < 8; kt++) {
            f32x4 h0 = __builtin_nontemporal_load(hp + kt * 8);
            f32x4 h1 = __builtin_nontemporal_load(hp + kt * 8 + 1);
            f32x4 t0 = __builtin_nontemporal_load(tp + kt * 8);
            f32x4 t1 = __builtin_nontemporal_load(tp + kt * 8 + 1);
            afr[kt] = pack8(h0 + t0, h1 + t1);
        }

        // h_tild: butterfly over the 16 mail rows (lane bits 0..3)
#pragma unroll
        for (int kt = 0; kt < 8; kt++) {
            float v[8];
#pragma unroll
            for (int e = 0; e < 8; e++) v[e] = mrow * b2f(afr[kt][e]);
#pragma unroll
            for (int m = 1; m < 16; m <<= 1) {
#pragma unroll
                for (int e = 0; e < 8; e++) v[e] += __shfl_xor(v[e], m, 64);
            }
            if (r15 == 0) {
                f32x4 w0 = {v[0], v[1], v[2], v[3]};
                f32x4 w1 = {v[4], v[5], v[6], v[7]};
                *reinterpret_cast<u16x8*>(htb + (size_t)n * 256 + kt * 32 + q * 8) = pack8(w0, w1);
            }
        }

        // f-GEMM + c_red
        const float* cmb = c_mail + ((size_t)n * 16 + q * 4) * 256 + r15;
        const float* xb = xwf + (size_t)n * 256 + r15;
        float mj0 = m4[0], mj1 = m4[1], mj2 = m4[2], mj3 = m4[3];
        for (int ct = 0; ct < 16; ct++) {
            float xv = xb[ct * 16];
            float cm0 = cmb[ct * 16];
            float cm1 = cmb[ct * 16 + 256];
            float cm2 = cmb[ct * 16 + 512];
            float cm3 = cmb[ct * 16 + 768];
            f32x4 acc = {xv, xv, xv, xv};
#pragma unroll
            for (int kt = 0; kt < 8; kt++) {
                u16x8 b = *reinterpret_cast<const u16x8*>(ufrag + ((size_t)(ct * 8 + kt) * 64 + lane) * 8);
                acc = __builtin_amdgcn_mfma_f32_16x16x32_bf16(asbf(afr[kt]), asbf(b), acc, 0, 0, 0);
            }
            float s = mj0 * sigm(acc[0]) * cm0 + mj1 * sigm(acc[1]) * cm1
                    + mj2 * sigm(acc[2]) * cm2 + mj3 * sigm(acc[3]) * cm3;
            s += __shfl_xor(s, 16, 64);
            s += __shfl_xor(s, 32, 64);
            if (lane < 16) c_redw[(size_t)n * 256 + ct * 16 + lane] = s;
        }
    }
}

// ---------------------------------------------------------------------------
// K2: iou = [h_tild | x] @ [U_iou | W_iou]^T + b_iou ; gates -> h, c
// Wave handles (group, ct-quad): 4 col-tiles x {i,o,u}; 5000 waves total.
// ---------------------------------------------------------------------------
__global__ __launch_bounds__(256, 4) void iou_final(
        const unsigned short* __restrict__ htb, const float* __restrict__ x,
        const float* __restrict__ c_redw, const unsigned short* __restrict__ b2frag,
        const float* __restrict__ biou, float* __restrict__ out) {
    int lane = threadIdx.x & 63;
    int wid = (blockIdx.x * blockDim.x + threadIdx.x) >> 6;
    int nw = (gridDim.x * blockDim.x) >> 6;
    int r15 = lane & 15, q = lane >> 4;
    const int NG = N_NODES / 16;
    const size_t NH = (size_t)N_NODES * 256;
    for (int t = wid; t < NG * 4; t += nw) {
        int grp = t >> 2, cq = t & 3;
        int n0 = grp * 16;
        u16x8 afr[16];
#pragma unroll
        for (int kt = 0; kt < 8; kt++)
            afr[kt] = *reinterpret_cast<const u16x8*>(htb + (size_t)(n0 + r15) * 256 + kt * 32 + q * 8);
        const f32x4* xp = reinterpret_cast<const f32x4*>(x + (size_t)(n0 + r15) * 256 + q * 8);
#pragma unroll
        for (int kt = 0; kt < 8; kt++) {
            f32x4 a0 = xp[kt * 8];
            f32x4 a1 = xp[kt * 8 + 1];
            afr[8 + kt] = pack8(a0, a1);
        }
#pragma unroll
        for (int cc = 0; cc < 4; cc++) {
            int ct = cq * 4 + cc;
            float cr[4];
#pragma unroll
            for (int j = 0; j < 4; j++)
                cr[j] = c_redw[(size_t)(n0 + q * 4 + j) * 256 + ct * 16 + r15];
            float bi = biou[ct * 16 + r15];
            float bo = biou[256 + ct * 16 + r15];
            float bu = biou[512 + ct * 16 + r15];
            f32x4 ai = {bi, bi, bi, bi};
            f32x4 ao = {bo, bo, bo, bo};
            f32x4 au = {bu, bu, bu, bu};
#pragma unroll
            for (int kt = 0; kt < 16; kt++) {
                u16x8 Bi = *reinterpret_cast<const u16x8*>(b2frag + ((size_t)((ct)      * 16 + kt) * 64 + lane) * 8);
                u16x8 Bo = *reinterpret_cast<const u16x8*>(b2frag + ((size_t)((16 + ct) * 16 + kt) * 64 + lane) * 8);
                u16x8 Bu = *reinterpret_cast<const u16x8*>(b2frag + ((size_t)((32 + ct) * 16 + kt) * 64 + lane) * 8);
                ai = __builtin_amdgcn_mfma_f32_16x16x32_bf16(asbf(afr[kt]), asbf(Bi), ai, 0, 0, 0);
                ao = __builtin_amdgcn_mfma_f32_16x16x32_bf16(asbf(afr[kt]), asbf(Bo), ao, 0, 0, 0);
                au = __builtin_amdgcn_mfma_f32_16x16x32_bf16(asbf(afr[kt]), asbf(Bu), au, 0, 0, 0);
            }
#pragma unroll
            for (int j = 0; j < 4; j++) {
                size_t o = (size_t)(n0 + q * 4 + j) * 256 + ct * 16 + r15;
                float c = sigm(ai[j]) * tanh_f(au[j]) + cr[j];
                float h = sigm(ao[j]) * tanh_f(c);
                __builtin_nontemporal_store(h, &out[o]);
                __builtin_nontemporal_store(c, &out[NH + o]);
            }
        }
    }
}

extern "C" void kernel_launch(void* const* d_in, const int* in_sizes, int n_in,
                              void* d_out, int out_size, void* d_ws, size_t ws_size,
                              hipStream_t stream) {
    const float* x         = (const float*)d_in[0];
    const float* h_mail    = (const float*)d_in[1];
    const float* c_mail    = (const float*)d_in[2];
    const float* time_mail = (const float*)d_in[3];
    const float* mask      = (const float*)d_in[4];
    const float* W_iou     = (const float*)d_in[5];
    const float* U_iou     = (const float*)d_in[6];
    const float* b_iou     = (const float*)d_in[7];
    const float* U_f       = (const float*)d_in[8];
    const float* W_f       = (const float*)d_in[9];
    const float* b_f       = (const float*)d_in[10];
    float* out = (float*)d_out;

    char* w = (char*)d_ws;
    unsigned short* ufrag  = (unsigned short*)(w);              // 128 KB
    unsigned short* wfrag  = (unsigned short*)(w + 131072);     // 128 KB
    unsigned short* b2frag = (unsigned short*)(w + 262144);     // 768 KB
    unsigned short* htb    = (unsigned short*)(w + 1048576);    // 10.24 MB
    float*          xwf    = (float*)(w + 11288576);            // 20.48 MB
    float*          c_redw = (float*)(w + 31768576);            // 20.48 MB

    prep_weights<<<512, 256, 0, stream>>>(U_f, W_f, U_iou, W_iou, ufrag, wfrag, b2frag);
    xwf_gemm<<<1250, 256, 0, stream>>>(x, wfrag, b_f, xwf);
    main_cell<<<2500, 256, 0, stream>>>(h_mail, c_mail, time_mail, mask, xwf, ufrag, htb, c_redw);
    iou_final<<<1250, 256, 0, stream>>>(htb, x, c_redw, b2frag, b_iou, out);
}